// Round 4
// baseline (1357.624 us; speedup 1.0000x reference)
//
#include <hip/hip_runtime.h>

// VQProsodyEncoder on gfx950: 13x conv1d(K=5) as implicit-GEMM f16 MFMA,
// maxpool(8), VQ via (-2*z.c + |c|^2) GEMM + argmin + gather.
// Activations: channel-last f16 [B][T+4][C] with 2-row zero halos.
// R6: 128(M) x 256(N) block tile, 4 waves of 64x128 -> 160 MFMA per wave per
// barrier-pair (32 per tap), 12 LDS reads per 32 MFMA (MFMA-pipe now top).
// Minimal-2-phase: B double-buffered (staged at phase start, full phase in
// flight -> barrier drain free); A frag-major single-buffer restaged from L2
// between two barriers at phase end (~400cy exposed). Conflict-free LDS
// (frag-major A, XOR-swizzled B).

typedef _Float16 f16;
typedef __attribute__((ext_vector_type(8))) _Float16 half8;
typedef __attribute__((ext_vector_type(4))) _Float16 half4;
typedef __attribute__((ext_vector_type(4))) float float4v;

__device__ __forceinline__ void async16(const void* g, void* l) {
  __builtin_amdgcn_global_load_lds(
      (const __attribute__((address_space(1))) void*)g,
      (__attribute__((address_space(3))) void*)l, 16, 0, 0);
}

// ---------------------------------------------------------------------------
// conv as implicit GEMM: Y[b,t,o] = sum_{kt,ci} W[kt][o][ci] * X[b][t+kt-2][ci]
// tile 128(M=o) x 256(N=b*t), BK=32, 4 waves 64x128, mfma_f32_16x16x32_f16.
// Wf is fragment-major: [NTAP][Cinp/32][Cout/16][64 lanes][8 f16].
template <int NTAP>
__global__ __launch_bounds__(256, 2) void conv_gemm(
    const f16* __restrict__ Xb,   // [B][T+4][Cinp], halo rows zeroed
    const f16* __restrict__ Wf,   // fragment-major weights
    const float* __restrict__ bias,  // [Cout]
    const f16* __restrict__ Res,  // [B][T+4][Cout] or null (residual add)
    float* __restrict__ Yf,       // [B][T][Cout] or null
    f16* __restrict__ Yb,         // [B][T+4][Cout] or null
    int Cinp, int Cout, int lgT, int tapshift, int relu)
{
  __shared__ __align__(16) f16 Als[NTAP * 8 * 512];  // frag-major A: 8KB/tap
  __shared__ __align__(16) f16 Bls[2][272 * 32];     // B dbuf: 2 x 17KB

  const int tid  = threadIdx.x;
  const int wave = tid >> 6;
  const int lane = tid & 63;
  const int T  = 1 << lgT;
  const int n0 = blockIdx.x << 8;   // 256-wide N tile
  const int o0 = blockIdx.y << 7;   // 128-wide M tile
  const int b  = n0 >> lgT;
  const int t0 = n0 & (T - 1);

  const int lane4 = lane >> 2;  // row-within-16 for B staging
  // B pre-swizzle (both-sides): physical slot (lane&3) of LDS row r*16+lane4
  // holds global slot (lane&3) ^ ((row>>1)&3) == (lane&3)^((lane>>3)&3).
  const int lkB = ((lane & 3) ^ ((lane >> 3) & 3)) << 3;

  const f16* gB0 = Xb + (size_t)(b * (T + 4) + t0) * Cinp + lkB;

  const int mB  = (wave & 1) * 64;    // wave M-offset
  const int nB  = (wave >> 1) * 128;  // wave N-offset
  const int r16 = lane & 15;
  const int g4  = lane >> 4;          // k-slot (8 f16) of this lane
  const int C32 = Cinp >> 5;
  const int OB  = Cout >> 4;
  const int fb  = (wave & 1) * 4;     // first A-frag within the tap's 8

  // fragment-major W: frag index (kt*C32+c32)*OB + ob, each frag 512 f16.
  const f16* gW = Wf + (((size_t)(o0 >> 4)) << 9) + lane * 8;

  float4v acc[4][8] = {};

  auto stageA = [&](int c32) {  // NTAP*8 rounds; NTAP*2 per wave (uniform)
#pragma unroll
    for (int r = wave; r < NTAP * 8; r += 4) {
      const int kt = r >> 3, frag = r & 7;
      async16(gW + (((size_t)((kt * C32 + c32) * OB) + frag) << 9),
              &Als[r * 512 + lane * 8]);
    }
  };
  auto stageB = [&](int p, int ci) {  // 17 rounds (272 rows; >=260 junk)
    for (int r = wave; r < 17; r += 4)
      async16(gB0 + (size_t)(r * 16 + lane4) * Cinp + ci,
              &Bls[p][r * 512 + lane * 8]);
  };

  stageA(0);
  stageB(0, 0);
  __syncthreads();  // prologue drain: staging visible

#pragma unroll 1
  for (int n = 0; n < C32; ++n) {
    if (n + 1 < C32) stageB((n + 1) & 1, (n + 1) << 5);  // full phase in flight
#pragma unroll
    for (int kt = 0; kt < NTAP; ++kt) {
      half8 af[4], bv[8];
#pragma unroll
      for (int i = 0; i < 4; ++i)
        af[i] = *(const half8*)&Als[(kt * 8 + fb + i) * 512 + lane * 8];
#pragma unroll
      for (int j = 0; j < 8; ++j) {
        const int row = nB + j * 16 + r16 + tapshift + kt;
        const int sl  = g4 ^ ((row >> 1) & 3);
        bv[j] = *(const half8*)&Bls[n & 1][row * 32 + sl * 8];
      }
      __builtin_amdgcn_s_setprio(1);
#pragma unroll
      for (int i = 0; i < 4; ++i)
#pragma unroll
        for (int j = 0; j < 8; ++j)
          acc[i][j] = __builtin_amdgcn_mfma_f32_16x16x32_f16(af[i], bv[j], acc[i][j], 0, 0, 0);
      __builtin_amdgcn_s_setprio(0);
    }
    if (n + 1 < C32) {
      __syncthreads();   // WAR: all waves' A reads complete
      stageA(n + 1);     // L2-resident; ~400cy exposed at next drain
      __syncthreads();   // RAW: per-wave vmcnt(0) + barrier -> A visible
    }
  }

  // epilogue: D[row][col]: col = lane&15, row = (lane>>4)*4 + reg
  const int col = lane & 15;
  const int qr4 = (lane >> 4) << 2;
#pragma unroll
  for (int i = 0; i < 4; ++i) {
    const int o = o0 + mB + i * 16 + qr4;
    const float4v bb = *(const float4v*)&bias[o];
#pragma unroll
    for (int j = 0; j < 8; ++j) {
      const int t = t0 + nB + j * 16 + col;
      float4v v = acc[i][j] + bb;
      if (relu) {
        v.x = fmaxf(v.x, 0.f); v.y = fmaxf(v.y, 0.f);
        v.z = fmaxf(v.z, 0.f); v.w = fmaxf(v.w, 0.f);
      }
      if (Res) {
        half4 r = *(const half4*)&Res[(size_t)(b * (T + 4) + t + 2) * Cout + o];
        v.x += (float)r.x; v.y += (float)r.y; v.z += (float)r.z; v.w += (float)r.w;
      }
      if (Yf) *(float4v*)&Yf[(size_t)(b * T + t) * Cout + o] = v;
      if (Yb) {
        half4 h;
        h.x = (f16)v.x; h.y = (f16)v.y; h.z = (f16)v.z; h.w = (f16)v.w;
        *(half4*)&Yb[(size_t)(b * (T + 4) + t + 2) * Cout + o] = h;
      }
    }
  }
}

// ---------------------------------------------------------------------------
// repack weights [L][O][I][5] f32 -> fragment-major f16:
// plane (l,kt): [(ci/32)][(o/16)][lane][8], lane supplies o=ob*16+(lane&15),
// ci = c32*32 + (lane>>4)*8 + e. Zero-padded for ci >= I.
__global__ void repack_w(const float* __restrict__ w,
                         f16* __restrict__ wp,
                         int O, int I, int Ip)
{
  const int lkt = blockIdx.y;
  const int l = lkt / 5, kt = lkt % 5;
  const float* wl = w + (size_t)l * O * I * 5;
  f16* wpl = wp + (size_t)lkt * O * Ip;
  const int OB = O >> 4;
  const int n = O * Ip;
  for (int m = blockIdx.x * 256 + threadIdx.x; m < n; m += gridDim.x * 256) {
    int e = m & 7, lane = (m >> 3) & 63, rest = m >> 9;
    int ob = rest % OB, c32 = rest / OB;
    int o  = ob * 16 + (lane & 15);
    int ci = c32 * 32 + ((lane >> 4) << 3) + e;
    float v = (ci < I) ? wl[((size_t)o * I + ci) * 5 + kt] : 0.f;
    wpl[m] = (f16)v;
  }
}

__global__ void cb_repack(const float* __restrict__ cb,  // [1024][256]
                          f16* __restrict__ wcb,          // frag-major -2c
                          float* __restrict__ cnorm)      // [1024] = |c|^2
{
  int o = blockIdx.x;
  int lane = threadIdx.x;  // 64
  float4v c = *(const float4v*)&cb[(size_t)o * 256 + lane * 4];
  float s = c.x * c.x + c.y * c.y + c.z * c.z + c.w * c.w;
  for (int off = 32; off > 0; off >>= 1) s += __shfl_down(s, off);
  if (lane == 0) cnorm[o] = s;
  // fragment-major scatter: OB = 64 (Cout=1024)
#pragma unroll
  for (int u = 0; u < 4; ++u) {
    int ci  = lane * 4 + u;
    int c32 = ci >> 5;
    int fl  = (o & 15) + (((ci >> 3) & 3) << 4);
    int e   = ci & 7;
    wcb[(((size_t)(c32 * 64 + (o >> 4)) << 6) + fl) * 8 + e] = (f16)(-2.f * c[u]);
  }
}

__global__ void mel_to_f16(const float* __restrict__ mel,  // [32][2048][80]
                           f16* __restrict__ out)           // [32][2052][96]
{
  int idx = blockIdx.x * 256 + threadIdx.x;
  if (idx >= 32 * 2052 * 12) return;
  int c8 = idx % 12;
  int r  = idx / 12;
  int tt = r % 2052;
  int b  = r / 2052;
  int t  = tt - 2;
  bool trow = (t >= 0) && (t < 2048);
  half8 hv;
#pragma unroll
  for (int e = 0; e < 8; ++e) {
    int m = c8 * 8 + e;
    float v = (trow && m < 80) ? mel[((size_t)b * 2048 + t) * 80 + m] : 0.f;
    hv[e] = (f16)v;
  }
  *(half8*)&out[((size_t)b * 2052 + tt) * 96 + c8 * 8] = hv;
}

__global__ void maxpool8(const f16* __restrict__ X,  // [32][2052][384]
                         f16* __restrict__ Y)         // [32][260][384]
{
  int idx = blockIdx.x * 256 + threadIdx.x;
  if (idx >= 32 * 256 * 48) return;
  int c8 = idx % 48;
  int r  = idx / 48;
  int tp = r % 256;
  int b  = r / 256;
  const f16* xp = &X[((size_t)b * 2052 + tp * 8 + 2) * 384 + c8 * 8];
  half8 m = *(const half8*)xp;
#pragma unroll
  for (int s = 1; s < 8; ++s) {
    half8 v = *(const half8*)(xp + (size_t)s * 384);
#pragma unroll
    for (int e = 0; e < 8; ++e) m[e] = (v[e] > m[e]) ? v[e] : m[e];
  }
  *(half8*)&Y[((size_t)b * 260 + tp + 2) * 384 + c8 * 8] = m;
}

__global__ void halo_zero(f16* a0, f16* a1, f16* b0, f16* b1, f16* zb,
                          float* accum)
{
  int bid = blockIdx.x;  // 5 bufs * 32 batches * 4 rows = 640
  if (bid == 0 && threadIdx.x == 0) { accum[0] = 0.f; accum[1] = 0.f; }
  int buf = bid >> 7;
  int r = bid & 127;
  int bb = r >> 2;
  int k = r & 3;
  f16* p; int T4, C;
  if      (buf == 0) { p = a0; T4 = 2052; C = 384; }
  else if (buf == 1) { p = a1; T4 = 2052; C = 384; }
  else if (buf == 2) { p = b0; T4 = 260;  C = 384; }
  else if (buf == 3) { p = b1; T4 = 260;  C = 384; }
  else               { p = zb; T4 = 260;  C = 256; }
  int tt = (k < 2) ? k : (T4 - 4 + k);
  f16* rowp = p + ((size_t)bb * T4 + tt) * C;
  for (int c = threadIdx.x; c < C; c += 256) rowp[c] = (f16)0.f;
}

__global__ void argmin_rows(const float* __restrict__ S,  // [8192][1024]
                            int* __restrict__ outIdx)
{
  int row = blockIdx.x * 4 + (threadIdx.x >> 6);
  int lane = threadIdx.x & 63;
  const float* sr = S + (size_t)row * 1024;
  float bv = 3.4e38f;
  int bi = 0;
#pragma unroll
  for (int g = 0; g < 4; ++g) {
    float4v v = *(const float4v*)&sr[g * 256 + lane * 4];
#pragma unroll
    for (int e = 0; e < 4; ++e) {
      float f = v[e];
      int id = g * 256 + lane * 4 + e;
      if (f < bv || (f == bv && id < bi)) { bv = f; bi = id; }
    }
  }
  for (int off = 32; off > 0; off >>= 1) {
    float ov = __shfl_down(bv, off);
    int oi = __shfl_down(bi, off);
    if (ov < bv || (ov == bv && oi < bi)) { bv = ov; bi = oi; }
  }
  if (lane == 0) outIdx[row] = bi;
}

__global__ void vq_gather(const float* __restrict__ zf,   // [8192][256]
                          const float* __restrict__ cb,   // [1024][256]
                          const int* __restrict__ idx,
                          float* __restrict__ zq,          // [8192][256]
                          float* __restrict__ accum)
{
  int row = blockIdx.x;
  int lane = threadIdx.x;  // 64
  int j = idx[row];
  float4v z = *(const float4v*)&zf[(size_t)row * 256 + lane * 4];
  float4v q = *(const float4v*)&cb[(size_t)j * 256 + lane * 4];
  *(float4v*)&zq[(size_t)row * 256 + lane * 4] = q;
  float4v d = z - q;
  float s = d.x * d.x + d.y * d.y + d.z * d.z + d.w * d.w;
  for (int off = 32; off > 0; off >>= 1) s += __shfl_down(s, off);
  if (lane == 0) atomicAdd(accum, s);
}

__global__ void finalize_loss(const float* __restrict__ accum,
                              float* __restrict__ out2)
{
  float c = accum[0] * (1.0f / 2097152.0f);  // mean over 32*256*256
  out2[0] = c;   // commit_loss
  out2[1] = c;   // vq_loss (== commit_loss numerically)
}

// ---------------------------------------------------------------------------
extern "C" void kernel_launch(void* const* d_in, const int* in_sizes, int n_in,
                              void* d_out, int out_size, void* d_ws, size_t ws_size,
                              hipStream_t stream)
{
  (void)in_sizes; (void)n_in; (void)out_size;
  const float* mel    = (const float*)d_in[0];
  const float* w_pre  = (const float*)d_in[1];
  const float* b_pre  = (const float*)d_in[2];
  const float* w_b1   = (const float*)d_in[3];
  const float* b_b1   = (const float*)d_in[4];
  const float* w_b2   = (const float*)d_in[5];
  const float* b_b2   = (const float*)d_in[6];
  const float* w_post = (const float*)d_in[7];
  const float* b_post = (const float*)d_in[8];
  const float* cbk    = (const float*)d_in[9];
  float* out = (float*)d_out;

  size_t off = 0;
  auto carve = [&](size_t bytes) -> char* {
    char* p = (char*)d_ws + off;
    off += (bytes + 255) & ~(size_t)255;
    return p;
  };
  f16*   wpPre  = (f16*)carve((size_t)5 * 384 * 96 * 2);
  f16*   wpB1   = (f16*)carve((size_t)6 * 5 * 384 * 384 * 2);
  f16*   wpB2   = (f16*)carve((size_t)6 * 5 * 384 * 384 * 2);
  f16*   wpPost = (f16*)carve((size_t)5 * 256 * 384 * 2);
  f16*   wpCb   = (f16*)carve((size_t)1024 * 256 * 2);
  float* cnorm  = (float*)carve(1024 * 4);
  float* accum  = (float*)carve(256);
  f16*   xmel   = (f16*)carve((size_t)32 * 2052 * 96 * 2);
  f16*   xa0    = (f16*)carve((size_t)32 * 2052 * 384 * 2);
  f16*   xa1    = (f16*)carve((size_t)32 * 2052 * 384 * 2);
  f16*   xb0    = (f16*)carve((size_t)32 * 260 * 384 * 2);
  f16*   xb1    = (f16*)carve((size_t)32 * 260 * 384 * 2);
  f16*   zeb    = (f16*)carve((size_t)32 * 260 * 256 * 2);
  float* zf     = (float*)carve((size_t)32 * 256 * 256 * 4);
  float* scores = (float*)carve((size_t)8192 * 1024 * 4);
  int*   idxb   = (int*)carve((size_t)8192 * 4);
  carve(65536);  // guard: B staging over-reads up to ~12 rows past last buffer
  if (off > ws_size) return;  // ~184 MB needed

  halo_zero<<<640, 256, 0, stream>>>(xa0, xa1, xb0, xb1, zeb, accum);
  repack_w<<<dim3(144, 5),  256, 0, stream>>>(w_pre,  wpPre,  384, 80,  96);
  repack_w<<<dim3(576, 30), 256, 0, stream>>>(w_b1,   wpB1,   384, 384, 384);
  repack_w<<<dim3(576, 30), 256, 0, stream>>>(w_b2,   wpB2,   384, 384, 384);
  repack_w<<<dim3(384, 5),  256, 0, stream>>>(w_post, wpPost, 256, 384, 384);
  cb_repack<<<1024, 64, 0, stream>>>(cbk, wpCb, cnorm);
  mel_to_f16<<<3078, 256, 0, stream>>>(mel, xmel);

  auto conv5 = [&](const f16* X, const f16* W, const float* bia, const f16* R,
                   float* YF, f16* YB, int Cinp, int Cout, int lgT, int relu) {
    dim3 g((32 << lgT) >> 8, Cout >> 7);
    conv_gemm<5><<<g, 256, 0, stream>>>(X, W, bia, R, YF, YB, Cinp, Cout, lgT,
                                        0, relu);
  };

  // pre-conv: relu(conv(mel))
  conv5(xmel, wpPre, b_pre, nullptr, nullptr, xa0, 96, 384, 11, 1);
  // stack 1 @ T=2048
  for (int i = 0; i < 6; ++i) {
    f16* in = (i & 1) ? xa1 : xa0;
    f16* o_ = (i & 1) ? xa0 : xa1;
    conv5(in, wpB1 + (size_t)i * 5 * 384 * 384, b_b1 + i * 384, in,
          nullptr, o_, 384, 384, 11, 1);
  }
  maxpool8<<<1536, 256, 0, stream>>>(xa0, xb0);
  // stack 2 @ T=256
  for (int i = 0; i < 6; ++i) {
    f16* in = (i & 1) ? xb1 : xb0;
    f16* o_ = (i & 1) ? xb0 : xb1;
    conv5(in, wpB2 + (size_t)i * 5 * 384 * 384, b_b2 + i * 384, in,
          nullptr, o_, 384, 384, 8, 1);
  }
  // post-conv: ze (f32 for loss, f16+halo for VQ scores)
  conv5(xb0, wpPost, b_post, nullptr, zf, zeb, 384, 256, 8, 0);
  // VQ scores: |c|^2 - 2 z.c  as a 1-tap "conv" (tapshift=2 = centered)
  {
    dim3 g((32 * 256) >> 8, 1024 >> 7);
    conv_gemm<1><<<g, 256, 0, stream>>>(zeb, wpCb, cnorm, nullptr, scores,
                                        nullptr, 256, 1024, 8, 2, 0);
  }

  argmin_rows<<<2048, 256, 0, stream>>>(scores, idxb);
  vq_gather<<<8192, 64, 0, stream>>>(zf, cbk, idxb, out, accum);
  finalize_loss<<<1, 1, 0, stream>>>(accum, out + 2097152);
}

// Round 6
// 1129.486 us; speedup vs baseline: 1.2020x; 1.2020x over previous
//
#include <hip/hip_runtime.h>

// VQProsodyEncoder on gfx950: 13x conv1d(K=5) as implicit-GEMM f16 MFMA,
// maxpool(8), VQ via (-2*z.c + |c|^2) GEMM + fused partial argmin + gather.
// Activations: channel-last f16 [B][T+4][C] with 2-row zero halos.
// R7 = R0's verified-best coarse structure (128x128 tile, 4 waves 64x64,
// A+B staged per c32 between two barriers, 80 MFMA per barrier pair,
// 49KB LDS -> 3 blocks/CU, 1536-block grid = exactly 2 rounds) combined with
// the verified conflict-free layouts from R1+ (fragment-major A: per-wave
// contiguous 1KB ds_read_b128; XOR-pre-swizzled B). R0 had 1.18e7 bank
// conflicts (~46K cyc/CU) as its only fixable deficiency; this removes them
// without touching the winning schedule. VQ scores no longer hit HBM:
// per-block 128-bin argmin partials are reduced in the epilogue.
// (R5 resubmit: previous round died on container acquisition, not kernel.)

typedef _Float16 f16;
typedef __attribute__((ext_vector_type(8))) _Float16 half8;
typedef __attribute__((ext_vector_type(4))) _Float16 half4;
typedef __attribute__((ext_vector_type(4))) float float4v;

__device__ __forceinline__ void async16(const void* g, void* l) {
  __builtin_amdgcn_global_load_lds(
      (const __attribute__((address_space(1))) void*)g,
      (__attribute__((address_space(3))) void*)l, 16, 0, 0);
}

// ---------------------------------------------------------------------------
// conv as implicit GEMM: Y[b,t,o] = sum_{kt,ci} W[kt][o][ci] * X[b][t+kt-2][ci]
// tile 128(M=o) x 128(N=b*t), BK=32, 4 waves 64x64, mfma_f32_16x16x32_f16.
// Wf is fragment-major: [NTAP][Cinp/32][Cout/16][64 lanes][8 f16].
template <int NTAP>
__global__ __launch_bounds__(256, 3) void conv_gemm(
    const f16* __restrict__ Xb,   // [B][T+4][Cinp], halo rows zeroed
    const f16* __restrict__ Wf,   // fragment-major weights
    const float* __restrict__ bias,  // [Cout]
    const f16* __restrict__ Res,  // [B][T+4][Cout] or null (residual add)
    float* __restrict__ Yf,       // [B][T][Cout] or null
    f16* __restrict__ Yb,         // [B][T+4][Cout] or null
    float2* __restrict__ Pmin,    // [N][gridDim.y] per-tile argmin or null
    int Cinp, int Cout, int lgT, int tapshift, int relu)
{
  __shared__ __align__(16) f16 Als[NTAP * 8 * 512];  // frag-major A: 8KB/tap
  __shared__ __align__(16) f16 Bls[144 * 32];        // 144 t-rows x 32 ci

  const int tid  = threadIdx.x;
  const int wave = tid >> 6;
  const int lane = tid & 63;
  const int T  = 1 << lgT;
  const int n0 = blockIdx.x << 7;
  const int o0 = blockIdx.y << 7;
  const int b  = n0 >> lgT;
  const int t0 = n0 & (T - 1);

  const int lane4 = lane >> 2;  // row-within-16 for B staging
  // B pre-swizzle (both-sides): physical slot (lane&3) of LDS row r*16+lane4
  // holds global slot (lane&3) ^ ((row>>1)&3) == (lane&3)^((lane>>3)&3).
  const int lkB = ((lane & 3) ^ ((lane >> 3) & 3)) << 3;

  const f16* gB0 = Xb + (size_t)(b * (T + 4) + t0) * Cinp + lkB;

  const int mB  = (wave & 1) * 64;
  const int nB  = (wave >> 1) * 64;
  const int r16 = lane & 15;
  const int g4  = lane >> 4;        // k-slot (8 f16) of this lane
  const int C32 = Cinp >> 5;
  const int OB  = Cout >> 4;
  const int fb  = (wave & 1) * 4;   // first A-frag within a tap's 8

  // fragment-major W: frag index (kt*C32+c32)*OB + ob, each frag 512 f16.
  const f16* gW = Wf + (((size_t)(o0 >> 4)) << 9) + lane * 8;

  float4v acc[4][4] = {};

#pragma unroll 1
  for (int c32 = 0; c32 < C32; ++c32) {
    __syncthreads();  // previous iteration's LDS reads complete
    // stage A: NTAP*8 frags of 1KB (frag-major, linear -> conflict-free)
#pragma unroll
    for (int r = wave; r < NTAP * 8; r += 4) {
      const int kt = r >> 3, frag = r & 7;
      async16(gW + (((size_t)((kt * C32 + c32) * OB) + frag) << 9),
              &Als[r * 512 + lane * 8]);
    }
    // stage B: 9 wave-rounds = 144 t-rows (rows >=132 junk, never read)
    for (int r = wave; r < 9; r += 4)
      async16(gB0 + (size_t)(r * 16 + lane4) * Cinp + (c32 << 5),
              &Bls[r * 512 + lane * 8]);
    __syncthreads();  // drains vmcnt: staging visible

#pragma unroll
    for (int kt = 0; kt < NTAP; ++kt) {
      half8 af[4], bv[4];
#pragma unroll
      for (int i = 0; i < 4; ++i)
        af[i] = *(const half8*)&Als[(kt * 8 + fb + i) * 512 + lane * 8];
#pragma unroll
      for (int j = 0; j < 4; ++j) {
        const int row = nB + j * 16 + r16 + tapshift + kt;
        const int sl  = g4 ^ ((row >> 1) & 3);
        bv[j] = *(const half8*)&Bls[row * 32 + sl * 8];
      }
      __builtin_amdgcn_s_setprio(1);
#pragma unroll
      for (int i = 0; i < 4; ++i)
#pragma unroll
        for (int j = 0; j < 4; ++j)
          acc[i][j] = __builtin_amdgcn_mfma_f32_16x16x32_f16(af[i], bv[j], acc[i][j], 0, 0, 0);
      __builtin_amdgcn_s_setprio(0);
    }
  }

  // epilogue: D[row][col]: col = lane&15, row = (lane>>4)*4 + reg
  const int col = lane & 15;
  const int qr4 = (lane >> 4) << 2;

  if (Pmin) {
    // VQ path: per-row argmin over this block's 128 bins (o0..o0+127).
    // Per lane, j indexes 4 t-values; reduce i x reg (16 bins) locally,
    // then across lane-groups (l, l+16, l+32, l+48), then across m-waves.
    float bv[4] = {3.4e38f, 3.4e38f, 3.4e38f, 3.4e38f};
    int   bi[4] = {0, 0, 0, 0};
#pragma unroll
    for (int i = 0; i < 4; ++i) {
      const int o = o0 + mB + i * 16 + qr4;
      const float4v bb = *(const float4v*)&bias[o];  // |c|^2
#pragma unroll
      for (int j = 0; j < 4; ++j) {
        float4v v = acc[i][j] + bb;
#pragma unroll
        for (int r = 0; r < 4; ++r) {
          const float f = v[r];
          const int id = o + r;
          if (f < bv[j] || (f == bv[j] && id < bi[j])) { bv[j] = f; bi[j] = id; }
        }
      }
    }
#pragma unroll
    for (int off = 32; off >= 16; off >>= 1)
#pragma unroll
      for (int j = 0; j < 4; ++j) {
        const float ov = __shfl_down(bv[j], off);
        const int   oi = __shfl_down(bi[j], off);
        if (ov < bv[j] || (ov == bv[j] && oi < bi[j])) { bv[j] = ov; bi[j] = oi; }
      }
    __syncthreads();  // all waves done with LDS -> reuse Als for candidates
    float2* cand = (float2*)Als;  // [128 t][2 m-waves]
    if (lane < 16)
#pragma unroll
      for (int j = 0; j < 4; ++j)
        cand[(nB + j * 16 + lane) * 2 + (wave & 1)] =
            make_float2(bv[j], __int_as_float(bi[j]));
    __syncthreads();
    if (tid < 128) {
      float2 c0 = cand[tid * 2 + 0], c1 = cand[tid * 2 + 1];
      int i0 = __float_as_int(c0.x < c1.x ? c0.y : c1.y);
      float v0 = fminf(c0.x, c1.x);
      if (c0.x == c1.x) i0 = min(__float_as_int(c0.y), __float_as_int(c1.y));
      Pmin[(size_t)(n0 + tid) * gridDim.y + blockIdx.y] =
          make_float2(v0, __int_as_float(i0));
    }
    return;
  }

#pragma unroll
  for (int i = 0; i < 4; ++i) {
    const int o = o0 + mB + i * 16 + qr4;
    const float4v bb = *(const float4v*)&bias[o];
#pragma unroll
    for (int j = 0; j < 4; ++j) {
      const int t = t0 + nB + j * 16 + col;
      float4v v = acc[i][j] + bb;
      if (relu) {
        v.x = fmaxf(v.x, 0.f); v.y = fmaxf(v.y, 0.f);
        v.z = fmaxf(v.z, 0.f); v.w = fmaxf(v.w, 0.f);
      }
      if (Res) {
        half4 r = *(const half4*)&Res[(size_t)(b * (T + 4) + t + 2) * Cout + o];
        v.x += (float)r.x; v.y += (float)r.y; v.z += (float)r.z; v.w += (float)r.w;
      }
      if (Yf) *(float4v*)&Yf[(size_t)(b * T + t) * Cout + o] = v;
      if (Yb) {
        half4 h;
        h.x = (f16)v.x; h.y = (f16)v.y; h.z = (f16)v.z; h.w = (f16)v.w;
        *(half4*)&Yb[(size_t)(b * (T + 4) + t + 2) * Cout + o] = h;
      }
    }
  }
}

// ---------------------------------------------------------------------------
// repack weights [L][O][I][5] f32 -> fragment-major f16:
// plane (l,kt): [(ci/32)][(o/16)][lane][8], lane supplies o=ob*16+(lane&15),
// ci = c32*32 + (lane>>4)*8 + e. Zero-padded for ci >= I.
__global__ void repack_w(const float* __restrict__ w,
                         f16* __restrict__ wp,
                         int O, int I, int Ip)
{
  const int lkt = blockIdx.y;
  const int l = lkt / 5, kt = lkt % 5;
  const float* wl = w + (size_t)l * O * I * 5;
  f16* wpl = wp + (size_t)lkt * O * Ip;
  const int OB = O >> 4;
  const int n = O * Ip;
  for (int m = blockIdx.x * 256 + threadIdx.x; m < n; m += gridDim.x * 256) {
    int e = m & 7, lane = (m >> 3) & 63, rest = m >> 9;
    int ob = rest % OB, c32 = rest / OB;
    int o  = ob * 16 + (lane & 15);
    int ci = c32 * 32 + ((lane >> 4) << 3) + e;
    float v = (ci < I) ? wl[((size_t)o * I + ci) * 5 + kt] : 0.f;
    wpl[m] = (f16)v;
  }
}

__global__ void cb_repack(const float* __restrict__ cb,  // [1024][256]
                          f16* __restrict__ wcb,          // frag-major -2c
                          float* __restrict__ cnorm)      // [1024] = |c|^2
{
  int o = blockIdx.x;
  int lane = threadIdx.x;  // 64
  float4v c = *(const float4v*)&cb[(size_t)o * 256 + lane * 4];
  float s = c.x * c.x + c.y * c.y + c.z * c.z + c.w * c.w;
  for (int off = 32; off > 0; off >>= 1) s += __shfl_down(s, off);
  if (lane == 0) cnorm[o] = s;
  // fragment-major scatter: OB = 64 (Cout=1024)
#pragma unroll
  for (int u = 0; u < 4; ++u) {
    int ci  = lane * 4 + u;
    int c32 = ci >> 5;
    int fl  = (o & 15) + (((ci >> 3) & 3) << 4);
    int e   = ci & 7;
    wcb[(((size_t)(c32 * 64 + (o >> 4)) << 6) + fl) * 8 + e] = (f16)(-2.f * c[u]);
  }
}

__global__ void mel_to_f16(const float* __restrict__ mel,  // [32][2048][80]
                           f16* __restrict__ out)           // [32][2052][96]
{
  int idx = blockIdx.x * 256 + threadIdx.x;
  if (idx >= 32 * 2052 * 12) return;
  int c8 = idx % 12;
  int r  = idx / 12;
  int tt = r % 2052;
  int b  = r / 2052;
  int t  = tt - 2;
  bool trow = (t >= 0) && (t < 2048);
  half8 hv;
#pragma unroll
  for (int e = 0; e < 8; ++e) {
    int m = c8 * 8 + e;
    float v = (trow && m < 80) ? mel[((size_t)b * 2048 + t) * 80 + m] : 0.f;
    hv[e] = (f16)v;
  }
  *(half8*)&out[((size_t)b * 2052 + tt) * 96 + c8 * 8] = hv;
}

__global__ void maxpool8(const f16* __restrict__ X,  // [32][2052][384]
                         f16* __restrict__ Y)         // [32][260][384]
{
  int idx = blockIdx.x * 256 + threadIdx.x;
  if (idx >= 32 * 256 * 48) return;
  int c8 = idx % 48;
  int r  = idx / 48;
  int tp = r % 256;
  int b  = r / 256;
  const f16* xp = &X[((size_t)b * 2052 + tp * 8 + 2) * 384 + c8 * 8];
  half8 m = *(const half8*)xp;
#pragma unroll
  for (int s = 1; s < 8; ++s) {
    half8 v = *(const half8*)(xp + (size_t)s * 384);
#pragma unroll
    for (int e = 0; e < 8; ++e) m[e] = (v[e] > m[e]) ? v[e] : m[e];
  }
  *(half8*)&Y[((size_t)b * 260 + tp + 2) * 384 + c8 * 8] = m;
}

__global__ void halo_zero(f16* a0, f16* a1, f16* b0, f16* b1, f16* zb,
                          float* accum)
{
  int bid = blockIdx.x;  // 5 bufs * 32 batches * 4 rows = 640
  if (bid == 0 && threadIdx.x == 0) { accum[0] = 0.f; accum[1] = 0.f; }
  int buf = bid >> 7;
  int r = bid & 127;
  int bb = r >> 2;
  int k = r & 3;
  f16* p; int T4, C;
  if      (buf == 0) { p = a0; T4 = 2052; C = 384; }
  else if (buf == 1) { p = a1; T4 = 2052; C = 384; }
  else if (buf == 2) { p = b0; T4 = 260;  C = 384; }
  else if (buf == 3) { p = b1; T4 = 260;  C = 384; }
  else               { p = zb; T4 = 260;  C = 256; }
  int tt = (k < 2) ? k : (T4 - 4 + k);
  f16* rowp = p + ((size_t)bb * T4 + tt) * C;
  for (int c = threadIdx.x; c < C; c += 256) rowp[c] = (f16)0.f;
}

__global__ void argmin_part(const float2* __restrict__ P,  // [8192][8]
                            int* __restrict__ outIdx)
{
  int row = blockIdx.x * 256 + threadIdx.x;
  if (row >= 8192) return;
  float bv = 3.4e38f;
  int bi = 0;
#pragma unroll
  for (int m = 0; m < 8; ++m) {
    float2 p = P[(size_t)row * 8 + m];
    int id = __float_as_int(p.y);
    if (p.x < bv || (p.x == bv && id < bi)) { bv = p.x; bi = id; }
  }
  outIdx[row] = bi;
}

__global__ void vq_gather(const float* __restrict__ zf,   // [8192][256]
                          const float* __restrict__ cb,   // [1024][256]
                          const int* __restrict__ idx,
                          float* __restrict__ zq,          // [8192][256]
                          float* __restrict__ accum)
{
  int row = blockIdx.x;
  int lane = threadIdx.x;  // 64
  int j = idx[row];
  float4v z = *(const float4v*)&zf[(size_t)row * 256 + lane * 4];
  float4v q = *(const float4v*)&cb[(size_t)j * 256 + lane * 4];
  *(float4v*)&zq[(size_t)row * 256 + lane * 4] = q;
  float4v d = z - q;
  float s = d.x * d.x + d.y * d.y + d.z * d.z + d.w * d.w;
  for (int off = 32; off > 0; off >>= 1) s += __shfl_down(s, off);
  if (lane == 0) atomicAdd(accum, s);
}

__global__ void finalize_loss(const float* __restrict__ accum,
                              float* __restrict__ out2)
{
  float c = accum[0] * (1.0f / 2097152.0f);  // mean over 32*256*256
  out2[0] = c;   // commit_loss
  out2[1] = c;   // vq_loss (== commit_loss numerically)
}

// ---------------------------------------------------------------------------
extern "C" void kernel_launch(void* const* d_in, const int* in_sizes, int n_in,
                              void* d_out, int out_size, void* d_ws, size_t ws_size,
                              hipStream_t stream)
{
  (void)in_sizes; (void)n_in; (void)out_size;
  const float* mel    = (const float*)d_in[0];
  const float* w_pre  = (const float*)d_in[1];
  const float* b_pre  = (const float*)d_in[2];
  const float* w_b1   = (const float*)d_in[3];
  const float* b_b1   = (const float*)d_in[4];
  const float* w_b2   = (const float*)d_in[5];
  const float* b_b2   = (const float*)d_in[6];
  const float* w_post = (const float*)d_in[7];
  const float* b_post = (const float*)d_in[8];
  const float* cbk    = (const float*)d_in[9];
  float* out = (float*)d_out;

  size_t off = 0;
  auto carve = [&](size_t bytes) -> char* {
    char* p = (char*)d_ws + off;
    off += (bytes + 255) & ~(size_t)255;
    return p;
  };
  f16*   wpPre  = (f16*)carve((size_t)5 * 384 * 96 * 2);
  f16*   wpB1   = (f16*)carve((size_t)6 * 5 * 384 * 384 * 2);
  f16*   wpB2   = (f16*)carve((size_t)6 * 5 * 384 * 384 * 2);
  f16*   wpPost = (f16*)carve((size_t)5 * 256 * 384 * 2);
  f16*   wpCb   = (f16*)carve((size_t)1024 * 256 * 2);
  float* cnorm  = (float*)carve(1024 * 4);
  float* accum  = (float*)carve(256);
  f16*   xmel   = (f16*)carve((size_t)32 * 2052 * 96 * 2);
  f16*   xa0    = (f16*)carve((size_t)32 * 2052 * 384 * 2);
  f16*   xa1    = (f16*)carve((size_t)32 * 2052 * 384 * 2);
  f16*   xb0    = (f16*)carve((size_t)32 * 260 * 384 * 2);
  f16*   xb1    = (f16*)carve((size_t)32 * 260 * 384 * 2);
  f16*   zeb    = (f16*)carve((size_t)32 * 260 * 256 * 2);
  float* zf     = (float*)carve((size_t)32 * 256 * 256 * 4);
  float2* part  = (float2*)carve((size_t)8192 * 8 * 8);
  int*   idxb   = (int*)carve((size_t)8192 * 4);
  carve(65536);  // guard: B staging over-reads up to ~12 rows past last buffer
  if (off > ws_size) return;  // ~152 MB needed

  halo_zero<<<640, 256, 0, stream>>>(xa0, xa1, xb0, xb1, zeb, accum);
  repack_w<<<dim3(144, 5),  256, 0, stream>>>(w_pre,  wpPre,  384, 80,  96);
  repack_w<<<dim3(576, 30), 256, 0, stream>>>(w_b1,   wpB1,   384, 384, 384);
  repack_w<<<dim3(576, 30), 256, 0, stream>>>(w_b2,   wpB2,   384, 384, 384);
  repack_w<<<dim3(384, 5),  256, 0, stream>>>(w_post, wpPost, 256, 384, 384);
  cb_repack<<<1024, 64, 0, stream>>>(cbk, wpCb, cnorm);
  mel_to_f16<<<3078, 256, 0, stream>>>(mel, xmel);

  auto conv5 = [&](const f16* X, const f16* W, const float* bia, const f16* R,
                   float* YF, f16* YB, int Cinp, int Cout, int lgT, int relu) {
    dim3 g((32 << lgT) >> 7, Cout >> 7);
    conv_gemm<5><<<g, 256, 0, stream>>>(X, W, bia, R, YF, YB, nullptr,
                                        Cinp, Cout, lgT, 0, relu);
  };

  // pre-conv: relu(conv(mel))
  conv5(xmel, wpPre, b_pre, nullptr, nullptr, xa0, 96, 384, 11, 1);
  // stack 1 @ T=2048
  for (int i = 0; i < 6; ++i) {
    f16* in = (i & 1) ? xa1 : xa0;
    f16* o_ = (i & 1) ? xa0 : xa1;
    conv5(in, wpB1 + (size_t)i * 5 * 384 * 384, b_b1 + i * 384, in,
          nullptr, o_, 384, 384, 11, 1);
  }
  maxpool8<<<1536, 256, 0, stream>>>(xa0, xb0);
  // stack 2 @ T=256
  for (int i = 0; i < 6; ++i) {
    f16* in = (i & 1) ? xb1 : xb0;
    f16* o_ = (i & 1) ? xb0 : xb1;
    conv5(in, wpB2 + (size_t)i * 5 * 384 * 384, b_b2 + i * 384, in,
          nullptr, o_, 384, 384, 8, 1);
  }
  // post-conv: ze (f32 for loss, f16+halo for VQ scores)
  conv5(xb0, wpPost, b_post, nullptr, zf, zeb, 384, 256, 8, 0);
  // VQ scores: |c|^2 - 2 z.c as 1-tap "conv" (tapshift=2 = centered), with
  // fused per-block 128-bin argmin -> part[8192][8]
  {
    dim3 g((32 * 256) >> 7, 1024 >> 7);
    conv_gemm<1><<<g, 256, 0, stream>>>(zeb, wpCb, cnorm, nullptr, nullptr,
                                        nullptr, part, 256, 1024, 8, 2, 0);
  }

  argmin_part<<<32, 256, 0, stream>>>(part, idxb);
  vq_gather<<<8192, 64, 0, stream>>>(zf, cbk, idxb, out, accum);
  finalize_loss<<<1, 1, 0, stream>>>(accum, out + 2097152);
}